// Round 1
// baseline (456.651 us; speedup 1.0000x reference)
//
#include <hip/hip_runtime.h>
#include <hip/hip_bf16.h>

#define BB 128
#define TT 512
#define EE 128
#define HH 256
#define MM 1024
#define CC 5

typedef _Float16 h2 __attribute__((ext_vector_type(2)));
typedef __fp16 f16x2 __attribute__((ext_vector_type(2)));
typedef __fp16 f16x8 __attribute__((ext_vector_type(8)));
typedef float  f32x4 __attribute__((ext_vector_type(4)));

__device__ inline h2 mkh2(float a, float b) {
    return __builtin_bit_cast(h2, __builtin_amdgcn_cvt_pkrtz(a, b));
}

// pack 8 f32 -> 8 f16 (one MFMA operand fragment)
__device__ inline f16x8 pack8(float4 lo, float4 hi) {
    union { f16x2 h[4]; f16x8 v; } u;
    u.h[0] = __builtin_amdgcn_cvt_pkrtz(lo.x, lo.y);
    u.h[1] = __builtin_amdgcn_cvt_pkrtz(lo.z, lo.w);
    u.h[2] = __builtin_amdgcn_cvt_pkrtz(hi.x, hi.y);
    u.h[3] = __builtin_amdgcn_cvt_pkrtz(hi.z, hi.w);
    return u.v;
}

__device__ inline float dot2f(h2 a, h2 b, float c) {
#if __has_builtin(__builtin_amdgcn_fdot2)
    return __builtin_amdgcn_fdot2(a, b, c, false);
#else
    return c + (float)a.x * (float)b.x + (float)a.y * (float)b.y;
#endif
}

// Quad butterfly sum via DPP (VALU pipe, no LDS traffic).
__device__ inline float dpp_add4(float x) {
    int t = __builtin_amdgcn_update_dpp(0, __builtin_bit_cast(int, x), 0xB1, 0xF, 0xF, true);
    x += __builtin_bit_cast(float, t);
    t = __builtin_amdgcn_update_dpp(0, __builtin_bit_cast(int, x), 0x4E, 0xF, 0xF, true);
    x += __builtin_bit_cast(float, t);
    return x;
}

__device__ inline float fast_tanh(float x) {
    float e = __expf(2.0f * x);
    return 1.0f - 2.0f / (e + 1.0f);
}

// ---------------------------------------------------------------------------
// K1 (MFMA GEMM): u[tok][ch] = bias[ch] + emb[x[tok]] @ W_ih^T, f16 out.
// All B*T=65536 tokens (no length masking — cheaper than the bookkeeping).
// Tile: 32 tokens x 256 ch per WG (2048 WGs), K=128. Wave w owns 64 ch
// (4 col-tiles); W_ih held as 16 B-fragments in regs (loaded once); emb rows
// gathered -> f16 LDS -> A-fragments; bias in C-init; LDS-transpose epilogue
// for coalesced dwordx4 stores of u.
// R7: A-stage (ldsA, 8KB) and transpose-out (ldsO, 16KB) are DISJOINT LDS
// regions — no read->write overlap window, one barrier removed. 24KB/block,
// still 2 blocks/CU.
// Layouts (m89/m120-verified): A[m=lane&15][k=quad*8+j],
// B[k=quad*8+j][n=lane&15], D col=lane&15 row=quad*4+reg.
// ---------------------------------------------------------------------------
__global__ __launch_bounds__(256, 2)
void k_embed(const int* __restrict__ x,
             const float* __restrict__ emb, const float* __restrict__ W_ih,
             const float* __restrict__ b_ih, const float* __restrict__ b_hh,
             _Float16* __restrict__ u)
{
    const int tb   = blockIdx.x;        // 32-token tile
    const int tid  = threadIdx.x;
    const int wv   = tid >> 6;
    const int lane = tid & 63;
    const int l15  = lane & 15;
    const int quad = lane >> 4;

    __shared__ __align__(16) char ldsA[32 * 256];   // 8KB f16 A-stage
    __shared__ __align__(16) char ldsO[32 * 512];   // 16KB f16 output tile

    // B fragments: B[k][n] = W_ih[n][k]; n = 64*wv + 16*ct + l15
    f16x8 bf[4][4];
    float bias[4];
    #pragma unroll
    for (int ct = 0; ct < 4; ++ct) {
        const int n = 64 * wv + 16 * ct + l15;
        const float* wp = W_ih + (size_t)n * EE;
        #pragma unroll
        for (int kc = 0; kc < 4; ++kc) {
            const float4* p = (const float4*)(wp + 32 * kc + 8 * quad);
            bf[ct][kc] = pack8(p[0], p[1]);
        }
        bias[ct] = b_ih[n] + b_hh[n];
    }

    // gather 32 emb rows -> f16 LDS A[32][128]
    {
        const int r = tid >> 3;          // row 0..31
        const int s = tid & 7;           // 16-float segment
        const int tok = x[tb * 32 + r];
        const float4* ep = (const float4*)(emb + (size_t)tok * EE + 16 * s);
        float4 a = ep[0], b = ep[1], c = ep[2], d = ep[3];
        *(f16x8*)(ldsA + r * 256 + 32 * s)      = pack8(a, b);
        *(f16x8*)(ldsA + r * 256 + 32 * s + 16) = pack8(c, d);
    }
    __syncthreads();

    f32x4 acc[2][4];
    #pragma unroll
    for (int rt = 0; rt < 2; ++rt)
        #pragma unroll
        for (int ct = 0; ct < 4; ++ct)
            acc[rt][ct] = (f32x4){bias[ct], bias[ct], bias[ct], bias[ct]};

    #pragma unroll
    for (int kc = 0; kc < 4; ++kc) {
        const int ko = (32 * kc + 8 * quad) * 2;
        f16x8 a0 = *(const f16x8*)(ldsA + (l15)      * 256 + ko);
        f16x8 a1 = *(const f16x8*)(ldsA + (16 + l15) * 256 + ko);
        #pragma unroll
        for (int ct = 0; ct < 4; ++ct) {
            acc[0][ct] = __builtin_amdgcn_mfma_f32_16x16x32_f16(a0, bf[ct][kc], acc[0][ct], 0, 0, 0);
            acc[1][ct] = __builtin_amdgcn_mfma_f32_16x16x32_f16(a1, bf[ct][kc], acc[1][ct], 0, 0, 0);
        }
    }

    // D -> ldsO [token][ch] f16 (16KB); disjoint from ldsA, no barrier needed
    #pragma unroll
    for (int rt = 0; rt < 2; ++rt) {
        #pragma unroll
        for (int ct = 0; ct < 4; ++ct) {
            const int chb = (64 * wv + 16 * ct + l15) * 2;
            #pragma unroll
            for (int rg = 0; rg < 4; ++rg) {
                const int tok = 16 * rt + 4 * quad + rg;
                *(_Float16*)(ldsO + tok * 512 + chb) = (_Float16)acc[rt][ct][rg];
            }
        }
    }
    __syncthreads();

    // coalesced writeout: 32 tokens x 512B = 16KB
    {
        char* dst = (char*)u + (size_t)tb * 16384 + tid * 64;
        const char* src = ldsO + tid * 64;
        #pragma unroll
        for (int q = 0; q < 4; ++q)
            *(float4*)(dst + 16 * q) = *(const float4*)(src + 16 * q);
    }
}

// ---------------------------------------------------------------------------
// K2 (fused scan + MLP head + log_softmax). One workgroup per batch element.
// Scan: split-K(4) + DPP, u staged in 64-step chunks (32KB LDS, coalesced);
// inner loop LDS-only so __syncthreads() has no vmcnt drain.
// R7: head fused in — thread tid ends the scan holding h[b][tid] in a
// register, so no hn workspace is needed at all. Workspace use is now
// EXACTLY B*T*H*2 = 32MiB (the old hn block at d_ws+32MiB wrote past a
// 32MiB workspace -> persistent corruption -> post-timing divergence).
// Bonus: short-len blocks run their head while long blocks still scan.
// ---------------------------------------------------------------------------
__global__ __launch_bounds__(256, 1)
void k_rnn_head(const int* __restrict__ lengths, const float* __restrict__ W_hh,
                const _Float16* __restrict__ u,
                const float* __restrict__ W0, const float* __restrict__ b0,
                const float* __restrict__ W1, const float* __restrict__ b1,
                float* __restrict__ out)
{
    const int b = blockIdx.x;
    const int tid = threadIdx.x;
    const int kc = tid & 3;
    const int g  = tid >> 2;
    const int len = lengths[b];

    h2 w[4][32];
    #pragma unroll
    for (int m = 0; m < 4; ++m) {
        const float4* wr = (const float4*)(W_hh + (size_t)(4*g + m) * HH + kc*64);
        #pragma unroll
        for (int q = 0; q < 16; ++q) {
            float4 v = wr[q];
            w[m][2*q]   = mkh2(v.x, v.y);
            w[m][2*q+1] = mkh2(v.z, v.w);
        }
    }

    __shared__ __align__(16) char hbuf[2][512];     // 2 x 256 f16 (b128-read!)
    __shared__ __align__(16) char ubuf[64 * 512];   // 64 steps x 256ch x 2B
    __shared__ __align__(16) float sh[HH];          // head: h row (f32)
    __shared__ __align__(16) float sh1[MM];         // head: relu(h@W0^T+b0)
    __shared__ float sred[CC][4];
    __shared__ float slog[CC];

    ((float*)hbuf)[tid] = 0.f;

    const int wr_off = (tid >> 6) * 128
                     + (((((tid >> 3) & 7) + 2 * (tid >> 6)) & 7) << 4)
                     + ((tid & 7) << 1);
    int roff[8];
    #pragma unroll
    for (int i = 0; i < 8; ++i)
        roff[i] = kc * 128 + (((i + 2 * kc) & 7) << 4);

    __syncthreads();

    float hlast = 0.f;
    if (len > 0) {
        const char* ubase = (const char*)(u + ((size_t)b * TT + (TT - len)) * HH);
        const int totbytes = len * 512;
        int p = 0;
        for (int c = 0; c * 64 < len; ++c) {
            const int cbase = c * 32768;
            float4 stash[8];
            #pragma unroll
            for (int q = 0; q < 8; ++q) {
                int off = cbase + q * 4096 + tid * 16;
                off = (off > totbytes - 16) ? (totbytes - 16) : off;
                stash[q] = *(const float4*)(ubase + off);
            }
            #pragma unroll
            for (int q = 0; q < 8; ++q)
                *(float4*)(ubuf + q * 4096 + tid * 16) = stash[q];
            __syncthreads();
            const int steps = (len - c * 64 < 64) ? (len - c * 64) : 64;
            for (int s = 0; s < steps; ++s) {
                const _Float16 uv = *(const _Float16*)(ubuf + s * 512 + tid * 2);
                const char* hb = hbuf[p];
                float a0 = 0.f, a1 = 0.f, a2 = 0.f, a3 = 0.f;
                #pragma unroll
                for (int i = 0; i < 8; ++i) {
                    float4 hv = *(const float4*)(hb + roff[i]);
                    h2* hp = (h2*)&hv;
                    #pragma unroll
                    for (int z = 0; z < 4; ++z) {
                        a0 = dot2f(w[0][4*i+z], hp[z], a0);
                        a1 = dot2f(w[1][4*i+z], hp[z], a1);
                        a2 = dot2f(w[2][4*i+z], hp[z], a2);
                        a3 = dot2f(w[3][4*i+z], hp[z], a3);
                    }
                }
                a0 = dpp_add4(a0); a1 = dpp_add4(a1);
                a2 = dpp_add4(a2); a3 = dpp_add4(a3);
                float v = (kc == 0) ? a0 : (kc == 1) ? a1
                        : (kc == 2) ? a2 : a3;
                const float hnew = fast_tanh(v + (float)uv);
                hlast = hnew;
                *(_Float16*)(hbuf[p ^ 1] + wr_off) = (_Float16)hnew;
                __syncthreads();
                p ^= 1;
            }
        }
    }

    // ---- fused MLP head + log_softmax (thread tid holds h[b][tid]) ----
    sh[tid] = hlast;
    __syncthreads();

    float acc[4];
    #pragma unroll
    for (int i = 0; i < 4; ++i) acc[i] = b0[tid + 256 * i];
    const float4* sh4 = (const float4*)sh;
    for (int k4 = 0; k4 < HH / 4; ++k4) {
        float4 hv = sh4[k4];
        #pragma unroll
        for (int i = 0; i < 4; ++i) {
            float4 wv = ((const float4*)(W0 + (size_t)(tid + 256 * i) * HH))[k4];
            acc[i] += wv.x * hv.x + wv.y * hv.y + wv.z * hv.z + wv.w * hv.w;
        }
    }
    #pragma unroll
    for (int i = 0; i < 4; ++i) sh1[tid + 256 * i] = fmaxf(acc[i], 0.f);
    __syncthreads();

    float pc[CC] = {0.f, 0.f, 0.f, 0.f, 0.f};
    for (int k = tid; k < MM; k += 256) {
        float hv = sh1[k];
        #pragma unroll
        for (int c = 0; c < CC; ++c) pc[c] += W1[(size_t)c * MM + k] * hv;
    }
    const int lane = tid & 63, wid = tid >> 6;
    #pragma unroll
    for (int c = 0; c < CC; ++c) {
        float v = pc[c];
        #pragma unroll
        for (int off = 32; off > 0; off >>= 1) v += __shfl_down(v, off, 64);
        if (lane == 0) sred[c][wid] = v;
    }
    __syncthreads();
    if (tid < CC) {
        float s = sred[tid][0] + sred[tid][1] + sred[tid][2] + sred[tid][3]
                + b1[tid];
        slog[tid] = fmaxf(s, 0.f);
    }
    __syncthreads();
    if (tid < CC) {
        float mx = slog[0];
        #pragma unroll
        for (int c = 1; c < CC; ++c) mx = fmaxf(mx, slog[c]);
        float se = 0.f;
        #pragma unroll
        for (int c = 0; c < CC; ++c) se += __expf(slog[c] - mx);
        out[(size_t)b * CC + tid] = slog[tid] - mx - __logf(se);
    }
}

// ---------------------------------------------------------------------------
extern "C" void kernel_launch(void* const* d_in, const int* in_sizes, int n_in,
                              void* d_out, int out_size, void* d_ws, size_t ws_size,
                              hipStream_t stream) {
    const int*   x       = (const int*)d_in[0];
    const int*   lengths = (const int*)d_in[1];
    const float* emb     = (const float*)d_in[2];
    const float* W_ih    = (const float*)d_in[3];
    const float* W_hh    = (const float*)d_in[4];
    const float* b_ih    = (const float*)d_in[5];
    const float* b_hh    = (const float*)d_in[6];
    const float* W0      = (const float*)d_in[7];
    const float* b0      = (const float*)d_in[8];
    const float* W1      = (const float*)d_in[9];
    const float* b1      = (const float*)d_in[10];
    float* out = (float*)d_out;

    // Workspace: u only — exactly BB*TT*HH*2 = 32 MiB. (hn eliminated; the
    // old hn block started at d_ws+32MiB and could write past the workspace.)
    _Float16* u = (_Float16*)d_ws;

    k_embed   <<<(BB * TT) / 32, 256, 0, stream>>>(x, emb, W_ih, b_ih, b_hh, u);
    k_rnn_head<<<BB, 256, 0, stream>>>(lengths, W_hh, u, W0, b0, W1, b1, out);
}